// Round 12
// baseline (187.613 us; speedup 1.0000x reference)
//
#include <hip/hip_runtime.h>
#include <hip/hip_bf16.h>

#define N_PTS 100000
#define KNN   16
#define NK    (N_PTS * KNN)
#define CIN   64
#define CMID  64
#define COUT  128

#define HSLC    64           // histogram slices (r4-proven)
#define SEG_CNT 25000        // counters per segment (4 segments cover 100k)
#define SEG_U32 12500

#define NCOPY 32             // spread-atomic copies (kills same-line RMW serialization)

// ---------------- ws layout (bytes) ----------------
// [0, +12,800,000)          pc: 64 x 100k ushort partials (dead after gemm1);
//                           reused as hb: N*64 bf16 = bf16(relu(z1*A1+B1))
// [13,000,000, +16,384)     SP1: [32][128] float stat1 partial copies (zeroed by hist)
// [13,100,000, +32,768)     SP2: [32][256] float stat2 partial copies (zeroed by hist)
// [25,600,000, +12,800,000) z1b (N*64 bf16, row-major)
// [38,400,000, +400,000)    counts (float, written by gemm1 for stats2)
// [38,801,536, +16,384)     W2bf: B-frag-swizzled W2 (bf16)
// [38,817,920, +8,192)      W1bf: B-frag-swizzled W1 (bf16)
#define OFF_PC    0
#define OFF_HB    0
#define OFF_SP1   13000000
#define OFF_SP2   13100000
#define OFF_Z1B   25600000
#define OFF_CNT   38400000
#define OFF_W2BF  38801536
#define OFF_W1BF  38817920

typedef __attribute__((ext_vector_type(8))) short bf16x8;
typedef __attribute__((ext_vector_type(4))) float f32x4;
union U8 { uint4 u; bf16x8 v; unsigned short s[8]; };

__device__ __forceinline__ unsigned short f2bf(float f) {
    unsigned u = __float_as_uint(f);
    unsigned r = (u + 0x7fffu + ((u >> 16) & 1u)) >> 16;   // RNE
    return (unsigned short)r;
}

// ---- D1. hist_k: 256 hist blocks + swizzle W2 (256) + swizzle W1 (257) + zero SP (258) ----
__global__ __launch_bounds__(256) void hist_k(const int* __restrict__ idx,
                                              unsigned short* __restrict__ pc,
                                              const float* __restrict__ W2,
                                              unsigned short* __restrict__ w2bf,
                                              const float* __restrict__ W1,
                                              unsigned short* __restrict__ w1bf,
                                              float* __restrict__ sp1,
                                              float* __restrict__ sp2) {
    if (blockIdx.x >= 256) {
        if (blockIdx.x == 256) {
            // B-frag: e = ((nt*2+kh)*64 + lane)*8 + j ; value = bf16(W2[k,n])
            for (int e = threadIdx.x; e < 8192; e += 256) {
                int j = e & 7, lane = (e >> 3) & 63, kh = (e >> 9) & 1, nt = e >> 10;
                int k = kh * 32 + (lane >> 4) * 8 + j;
                int n = nt * 16 + (lane & 15);
                w2bf[e] = f2bf(W2[k * COUT + n]);
            }
        } else if (blockIdx.x == 257) {
            for (int e = threadIdx.x; e < 4096; e += 256) {
                int j = e & 7, lane = (e >> 3) & 63, kh = (e >> 9) & 1, nt = e >> 10;
                int k = kh * 32 + (lane >> 4) * 8 + j;
                int n = nt * 16 + (lane & 15);
                w1bf[e] = f2bf(W1[k * CMID + n]);
            }
        } else {
            for (int i = threadIdx.x; i < NCOPY * 128; i += 256) sp1[i] = 0.f;
            for (int i = threadIdx.x; i < NCOPY * 256; i += 256) sp2[i] = 0.f;
        }
        return;
    }
    __shared__ unsigned int smem[SEG_U32];     // 50 KB
    int seg  = blockIdx.x & 3;
    int slc  = blockIdx.x >> 2;                // 0..63
    int base = seg * SEG_CNT;

    for (int i = threadIdx.x; i < SEG_U32; i += 256) smem[i] = 0;
    __syncthreads();

    const int4* ip = (const int4*)idx;
    const int per = NK / 4 / HSLC;             // 6250 int4 per slice
    int s = slc * per, e = s + per;
    for (int i = s + threadIdx.x; i < e; i += 256) {
        int4 v = ip[i];
        int a;
        a = v.x - base; if ((unsigned)a < (unsigned)SEG_CNT)
            atomicAdd(&smem[a >> 1], 1u << ((a & 1) * 16));
        a = v.y - base; if ((unsigned)a < (unsigned)SEG_CNT)
            atomicAdd(&smem[a >> 1], 1u << ((a & 1) * 16));
        a = v.z - base; if ((unsigned)a < (unsigned)SEG_CNT)
            atomicAdd(&smem[a >> 1], 1u << ((a & 1) * 16));
        a = v.w - base; if ((unsigned)a < (unsigned)SEG_CNT)
            atomicAdd(&smem[a >> 1], 1u << ((a & 1) * 16));
    }
    __syncthreads();

    unsigned int* outp = (unsigned int*)(pc + (size_t)slc * N_PTS) + seg * SEG_U32;
    for (int i = threadIdx.x; i < SEG_U32; i += 256) outp[i] = smem[i];
}

// ---- D2. gemm1_k: derives counts from pc in-wave; z1b = bf16(feat@W1+b1); stats1 ----
// GRID 2048: T-lat retest with the atomic-tail confounder removed (r10's base at
// 8 waves/SIMD was ~22.6 us; spread-atomic tail at 2048 is ~1 us since the
// coalesced 64-lane consecutive atomics collapse to ~4 line-RMWs/wave).
__global__ __launch_bounds__(256) void gemm1_k(const float* __restrict__ feat,
                                               const unsigned short* __restrict__ w1bf,
                                               const float* __restrict__ b1,
                                               const unsigned short* __restrict__ pc,
                                               float* __restrict__ counts,
                                               unsigned short* __restrict__ z1b,
                                               float* __restrict__ sp1) {
    int lane = threadIdx.x & 63, wid = threadIdx.x >> 6;
    int il = lane & 15, quad = lane >> 4;

    bf16x8 wf[4][2];
    const uint4* wp = (const uint4*)w1bf;
    #pragma unroll
    for (int nt = 0; nt < 4; nt++) {
        U8 t0; t0.u = wp[(nt * 2 + 0) * 64 + lane]; wf[nt][0] = t0.v;
        U8 t1; t1.u = wp[(nt * 2 + 1) * 64 + lane]; wf[nt][1] = t1.v;
    }
    float bias[4];
    #pragma unroll
    for (int nt = 0; nt < 4; nt++) bias[nt] = b1[nt * 16 + il];

    float s[4] = {0, 0, 0, 0}, q[4] = {0, 0, 0, 0};

    int wgid = blockIdx.x * 4 + wid;
    for (int tile = wgid; tile < N_PTS / 16; tile += gridDim.x * 4) {
        int m0 = tile * 16;

        // ---- counts for rows m0..+16 from pc (lane = slice) ----
        const uint4* pcp = (const uint4*)(pc + (size_t)lane * N_PTS + m0);
        uint4 pa = pcp[0], pb = pcp[1];        // 16 packed u16 rows for slice 'lane'
        #pragma unroll
        for (int m = 1; m < 64; m <<= 1) {
            pa.x += __shfl_xor(pa.x, m, 64);
            pa.y += __shfl_xor(pa.y, m, 64);
            pa.z += __shfl_xor(pa.z, m, 64);
            pa.w += __shfl_xor(pa.w, m, 64);
            pb.x += __shfl_xor(pb.x, m, 64);
            pb.y += __shfl_xor(pb.y, m, 64);
            pb.z += __shfl_xor(pb.z, m, 64);
            pb.w += __shfl_xor(pb.w, m, 64);
        }
        // rows quad*4..+4 live in packed words 2q, 2q+1
        unsigned w0 = (quad == 0) ? pa.x : (quad == 1) ? pa.z : (quad == 2) ? pb.x : pb.z;
        unsigned w1 = (quad == 0) ? pa.y : (quad == 1) ? pa.w : (quad == 2) ? pb.y : pb.w;
        float4 cnt4;
        cnt4.x = (float)(w0 & 0xffffu);
        cnt4.y = (float)(w0 >> 16);
        cnt4.z = (float)(w1 & 0xffffu);
        cnt4.w = (float)(w1 >> 16);
        if (il == 0) ((float4*)(counts + m0))[quad] = cnt4;   // for stats2

        const float* fr = feat + (size_t)(m0 + il) * 64;
        float4 fa = *(const float4*)(fr + quad * 8);
        float4 fb = *(const float4*)(fr + quad * 8 + 4);
        float4 fc = *(const float4*)(fr + 32 + quad * 8);
        float4 fd = *(const float4*)(fr + 32 + quad * 8 + 4);
        U8 ua, ub;
        ua.s[0] = f2bf(fa.x); ua.s[1] = f2bf(fa.y); ua.s[2] = f2bf(fa.z); ua.s[3] = f2bf(fa.w);
        ua.s[4] = f2bf(fb.x); ua.s[5] = f2bf(fb.y); ua.s[6] = f2bf(fb.z); ua.s[7] = f2bf(fb.w);
        ub.s[0] = f2bf(fc.x); ub.s[1] = f2bf(fc.y); ub.s[2] = f2bf(fc.z); ub.s[3] = f2bf(fc.w);
        ub.s[4] = f2bf(fd.x); ub.s[5] = f2bf(fd.y); ub.s[6] = f2bf(fd.z); ub.s[7] = f2bf(fd.w);

        #pragma unroll
        for (int nt = 0; nt < 4; nt++) {
            f32x4 acc = {bias[nt], bias[nt], bias[nt], bias[nt]};
            acc = __builtin_amdgcn_mfma_f32_16x16x32_bf16(ua.v, wf[nt][0], acc, 0, 0, 0);
            acc = __builtin_amdgcn_mfma_f32_16x16x32_bf16(ub.v, wf[nt][1], acc, 0, 0, 0);
            // C/D: col = il (channel nt*16+il), row = m0 + quad*4 + reg
            unsigned short* zp = z1b + (size_t)(m0 + quad * 4) * 64 + nt * 16 + il;
            zp[0]   = f2bf(acc[0]);
            zp[64]  = f2bf(acc[1]);
            zp[128] = f2bf(acc[2]);
            zp[192] = f2bf(acc[3]);
            s[nt] += cnt4.x * acc[0] + cnt4.y * acc[1] + cnt4.z * acc[2] + cnt4.w * acc[3];
            q[nt] += cnt4.x * acc[0] * acc[0] + cnt4.y * acc[1] * acc[1]
                   + cnt4.z * acc[2] * acc[2] + cnt4.w * acc[3] * acc[3];
        }
    }
    #pragma unroll
    for (int m = 16; m <= 32; m <<= 1) {
        #pragma unroll
        for (int nt = 0; nt < 4; nt++) {
            s[nt] += __shfl_xor(s[nt], m, 64);
            q[nt] += __shfl_xor(q[nt], m, 64);
        }
    }
    __shared__ float sred[2][4][4][16];        // [s/q][wave][nt][il]
    if (quad == 0) {
        #pragma unroll
        for (int nt = 0; nt < 4; nt++) { sred[0][wid][nt][il] = s[nt]; sred[1][wid][nt][il] = q[nt]; }
    }
    __syncthreads();
    if (threadIdx.x < 128) {
        int which = threadIdx.x >> 6, c = threadIdx.x & 63;
        float t = sred[which][0][c >> 4][c & 15] + sred[which][1][c >> 4][c & 15]
                + sred[which][2][c >> 4][c & 15] + sred[which][3][c >> 4][c & 15];
        // spread-atomic: copy = bid & 31; layout sp1[copy][which*64 + c]
        atomicAdd(&sp1[(blockIdx.x & (NCOPY - 1)) * 128 + threadIdx.x], t);
    }
}

// ---- D3. stats2_k: sums SP1 copies -> BN1 coeffs; hb = bf16(relu(z1*A1+B1)); SP2 ----
// GRID 2048: same T-lat retest.
__device__ __forceinline__ bf16x8 bnrelu(uint4 r, float4 alo, float4 ahi,
                                         float4 blo, float4 bhi) {
    float z0 = __uint_as_float(r.x << 16), z1 = __uint_as_float(r.x & 0xffff0000u);
    float z2 = __uint_as_float(r.y << 16), z3 = __uint_as_float(r.y & 0xffff0000u);
    float z4 = __uint_as_float(r.z << 16), z5 = __uint_as_float(r.z & 0xffff0000u);
    float z6 = __uint_as_float(r.w << 16), z7 = __uint_as_float(r.w & 0xffff0000u);
    U8 o;
    o.s[0] = f2bf(fmaxf(fmaf(alo.x, z0, blo.x), 0.f));
    o.s[1] = f2bf(fmaxf(fmaf(alo.y, z1, blo.y), 0.f));
    o.s[2] = f2bf(fmaxf(fmaf(alo.z, z2, blo.z), 0.f));
    o.s[3] = f2bf(fmaxf(fmaf(alo.w, z3, blo.w), 0.f));
    o.s[4] = f2bf(fmaxf(fmaf(ahi.x, z4, bhi.x), 0.f));
    o.s[5] = f2bf(fmaxf(fmaf(ahi.y, z5, bhi.y), 0.f));
    o.s[6] = f2bf(fmaxf(fmaf(ahi.z, z6, bhi.z), 0.f));
    o.s[7] = f2bf(fmaxf(fmaf(ahi.w, z7, bhi.w), 0.f));
    return o.v;
}

__global__ __launch_bounds__(256) void stats2_k(const unsigned short* __restrict__ z1b,
                                                const unsigned short* __restrict__ w2bf,
                                                const float* __restrict__ sp1,
                                                const float* __restrict__ g1,
                                                const float* __restrict__ be1,
                                                const float* __restrict__ b2,
                                                const float* __restrict__ counts,
                                                unsigned short* __restrict__ hb,
                                                float* __restrict__ sp2) {
    __shared__ float Sl[128];                  // summed S1[0..63], Q1[64..127]
    __shared__ float Al[64], Bl[64];
    if (threadIdx.x < 128) {
        float t = 0.f;
        #pragma unroll
        for (int k = 0; k < NCOPY; k++) t += sp1[k * 128 + threadIdx.x];
        Sl[threadIdx.x] = t;
    }
    __syncthreads();
    if (threadIdx.x < 64) {
        const float inv = 1.0f / (float)NK;
        float m = Sl[threadIdx.x] * inv;
        float v = Sl[64 + threadIdx.x] * inv - m * m;
        float a = g1[threadIdx.x] * rsqrtf(v + 1e-5f);
        Al[threadIdx.x] = a;
        Bl[threadIdx.x] = be1[threadIdx.x] - m * a;
    }
    __syncthreads();

    int lane = threadIdx.x & 63, wid = threadIdx.x >> 6;
    int il = lane & 15, quad = lane >> 4;

    float4 a0lo = *(const float4*)(Al + quad * 8);
    float4 a0hi = *(const float4*)(Al + quad * 8 + 4);
    float4 b0lo = *(const float4*)(Bl + quad * 8);
    float4 b0hi = *(const float4*)(Bl + quad * 8 + 4);
    float4 a1lo = *(const float4*)(Al + 32 + quad * 8);
    float4 a1hi = *(const float4*)(Al + 32 + quad * 8 + 4);
    float4 b1lo = *(const float4*)(Bl + 32 + quad * 8);
    float4 b1hi = *(const float4*)(Bl + 32 + quad * 8 + 4);

    bf16x8 bfr[8][2];
    const uint4* wp = (const uint4*)w2bf;
    #pragma unroll
    for (int nt = 0; nt < 8; nt++) {
        U8 t0; t0.u = wp[(nt * 2 + 0) * 64 + lane]; bfr[nt][0] = t0.v;
        U8 t1; t1.u = wp[(nt * 2 + 1) * 64 + lane]; bfr[nt][1] = t1.v;
    }
    float bias[8];
    #pragma unroll
    for (int nt = 0; nt < 8; nt++) bias[nt] = b2[nt * 16 + il];

    float s[8], q[8];
    #pragma unroll
    for (int j = 0; j < 8; j++) { s[j] = 0.f; q[j] = 0.f; }

    int wgid = blockIdx.x * 4 + wid;
    for (int tile = wgid; tile < N_PTS / 16; tile += gridDim.x * 4) {
        int m0 = tile * 16;
        const uint4* ar = (const uint4*)(z1b + (size_t)(m0 + il) * 64);
        uint4 ra0 = ar[quad];
        uint4 ra1 = ar[4 + quad];
        bf16x8 af0 = bnrelu(ra0, a0lo, a0hi, b0lo, b0hi);
        bf16x8 af1 = bnrelu(ra1, a1lo, a1hi, b1lo, b1hi);
        // persist hb for the fused gather (MFMA-ready bf16, same values fed below)
        U8 o0; o0.v = af0;
        U8 o1; o1.v = af1;
        uint4* hp = (uint4*)(hb + (size_t)(m0 + il) * 64);
        hp[quad]     = o0.u;
        hp[4 + quad] = o1.u;
        float4 cnt4 = *(const float4*)(counts + m0 + quad * 4);
        #pragma unroll
        for (int nt = 0; nt < 8; nt++) {
            f32x4 acc = {bias[nt], bias[nt], bias[nt], bias[nt]};
            acc = __builtin_amdgcn_mfma_f32_16x16x32_bf16(af0, bfr[nt][0], acc, 0, 0, 0);
            acc = __builtin_amdgcn_mfma_f32_16x16x32_bf16(af1, bfr[nt][1], acc, 0, 0, 0);
            s[nt] += cnt4.x * acc[0] + cnt4.y * acc[1] + cnt4.z * acc[2] + cnt4.w * acc[3];
            q[nt] += cnt4.x * acc[0] * acc[0] + cnt4.y * acc[1] * acc[1]
                   + cnt4.z * acc[2] * acc[2] + cnt4.w * acc[3] * acc[3];
        }
    }
    #pragma unroll
    for (int m = 16; m <= 32; m <<= 1) {
        #pragma unroll
        for (int nt = 0; nt < 8; nt++) {
            s[nt] += __shfl_xor(s[nt], m, 64);
            q[nt] += __shfl_xor(q[nt], m, 64);
        }
    }
    __shared__ float sred[2][4][8][16];        // [s/q][wave][nt][il]
    if (quad == 0) {
        #pragma unroll
        for (int nt = 0; nt < 8; nt++) { sred[0][wid][nt][il] = s[nt]; sred[1][wid][nt][il] = q[nt]; }
    }
    __syncthreads();
    {
        int which = threadIdx.x >> 7, c = threadIdx.x & 127;
        float t = sred[which][0][c >> 4][c & 15] + sred[which][1][c >> 4][c & 15]
                + sred[which][2][c >> 4][c & 15] + sred[which][3][c >> 4][c & 15];
        // spread-atomic: layout sp2[copy][which*128 + c]
        atomicAdd(&sp2[(blockIdx.x & (NCOPY - 1)) * 256 + threadIdx.x], t);
    }
}

// ---- D4. fused gather(hb) + MFMA gemm2 + max + BN2 + relu + out (frozen, r11-proven) ----
__global__ __launch_bounds__(256) void fused_k(const unsigned short* __restrict__ hb,
                                               const unsigned short* __restrict__ w2bf,
                                               const int* __restrict__ idx,
                                               const float* __restrict__ b2,
                                               const float* __restrict__ sp2,
                                               const float* __restrict__ g2,
                                               const float* __restrict__ be2,
                                               float* __restrict__ out) {
    __shared__ float S2l[256];                 // summed S2[0..127], Q2[128..255]
    __shared__ float A2s[128], B2f[128];
    __shared__ uint4 wlds[1024];               // 16 KB staged (sign-folded) W2 B-frags

    {
        float t = 0.f;
        #pragma unroll
        for (int k = 0; k < NCOPY; k++) t += sp2[k * 256 + threadIdx.x];
        S2l[threadIdx.x] = t;
    }
    __syncthreads();
    const float inv = 1.0f / (float)NK;
    if (threadIdx.x < 128) {
        int c = threadIdx.x;
        float m = S2l[c] * inv;
        float v = S2l[128 + c] * inv - m * m;
        float a = g2[c] * rsqrtf(v + 1e-5f);
        A2s[c] = a;
        B2f[c] = fmaf(a, b2[c], be2[c] - m * a);   // fold b2: max(z2)=max(raw)+b2
    }
    __syncthreads();

    // stage W2 frags, flipping column sign where a2<0 (sign-fold: kills min path)
    for (int i = threadIdx.x; i < 1024; i += 256) {
        uint4 w = ((const uint4*)w2bf)[i];
        int n_ = ((i >> 7) << 4) + (i & 15);
        if (A2s[n_] < 0.f) {
            w.x ^= 0x80008000u; w.y ^= 0x80008000u;
            w.z ^= 0x80008000u; w.w ^= 0x80008000u;
        }
        wlds[i] = w;
    }
    __syncthreads();

    int lane = threadIdx.x & 63, wid = threadIdx.x >> 6;
    int il = lane & 15, quad = lane >> 4;

    bf16x8 bfr[8][2];
    #pragma unroll
    for (int nt = 0; nt < 8; nt++) {
        U8 t0; t0.u = wlds[(nt * 2 + 0) * 64 + lane]; bfr[nt][0] = t0.v;
        U8 t1; t1.u = wlds[(nt * 2 + 1) * 64 + lane]; bfr[nt][1] = t1.v;
    }
    float a2c[8], b2c[8];
    #pragma unroll
    for (int nt = 0; nt < 8; nt++) {
        a2c[nt] = fabsf(A2s[nt * 16 + il]);
        b2c[nt] = B2f[nt * 16 + il];
    }

    const int stride = gridDim.x * 4;
    int n  = blockIdx.x * 4 + wid;
    int n1 = n + stride;

    uint4 r0c = {0, 0, 0, 0}, r1c = {0, 0, 0, 0};
    if (n < N_PTS) {
        int j0 = idx[(size_t)n * KNN + il];
        const uint4* zr = (const uint4*)(hb + (size_t)j0 * 64);
        r0c = zr[quad];
        r1c = zr[4 + quad];
    }
    int j1 = (n1 < N_PTS) ? idx[(size_t)n1 * KNN + il] : 0;

    while (n < N_PTS) {
        uint4 r0n = {0, 0, 0, 0}, r1n = {0, 0, 0, 0};
        int n2 = n1 + stride;
        if (n1 < N_PTS) {
            const uint4* zr = (const uint4*)(hb + (size_t)j1 * 64);
            r0n = zr[quad];
            r1n = zr[4 + quad];
        }
        int j2 = (n2 < N_PTS) ? idx[(size_t)n2 * KNN + il] : 0;

        U8 ua, ub; ua.u = r0c; ub.u = r1c;
        float w0 = 0.f, w1 = 0.f;
        #pragma unroll
        for (int nt = 0; nt < 8; nt++) {
            f32x4 acc = {0.f, 0.f, 0.f, 0.f};
            acc = __builtin_amdgcn_mfma_f32_16x16x32_bf16(ua.v, bfr[nt][0], acc, 0, 0, 0);
            acc = __builtin_amdgcn_mfma_f32_16x16x32_bf16(ub.v, bfr[nt][1], acc, 0, 0, 0);
            float t = fmaxf(fmaxf(acc[0], acc[1]), fmaxf(acc[2], acc[3]));
            t = fmaxf(t, __shfl_xor(t, 16, 64));
            t = fmaxf(t, __shfl_xor(t, 32, 64));
            float v = fmaxf(fmaf(a2c[nt], t, b2c[nt]), 0.f);
            if (nt == quad)     w0 = v;
            if (nt == quad + 4) w1 = v;
        }
        float* op = out + (size_t)n * COUT;
        __builtin_nontemporal_store(w0, op + quad * 16 + il);       // ch 0..63
        __builtin_nontemporal_store(w1, op + 64 + quad * 16 + il);  // ch 64..127

        n = n1; n1 = n2; j1 = j2;
        r0c = r0n; r1c = r1n;
    }
}

extern "C" void kernel_launch(void* const* d_in, const int* in_sizes, int n_in,
                              void* d_out, int out_size, void* d_ws, size_t ws_size,
                              hipStream_t stream) {
    const float* feat = (const float*)d_in[0];
    const int*   idx  = (const int*)d_in[1];
    const float* W1   = (const float*)d_in[2];
    const float* b1   = (const float*)d_in[3];
    const float* g1   = (const float*)d_in[4];
    const float* be1  = (const float*)d_in[5];
    const float* W2   = (const float*)d_in[6];
    const float* b2   = (const float*)d_in[7];
    const float* g2   = (const float*)d_in[8];
    const float* be2  = (const float*)d_in[9];
    float* out = (float*)d_out;

    char* ws = (char*)d_ws;
    unsigned short* pc  = (unsigned short*)(ws + OFF_PC);
    unsigned short* hb  = (unsigned short*)(ws + OFF_HB);    // alias, pc dead after gemm1
    float* sp1 = (float*)(ws + OFF_SP1);
    float* sp2 = (float*)(ws + OFF_SP2);
    unsigned short* z1b = (unsigned short*)(ws + OFF_Z1B);
    float* counts = (float*)(ws + OFF_CNT);
    unsigned short* w2bf = (unsigned short*)(ws + OFF_W2BF);
    unsigned short* w1bf = (unsigned short*)(ws + OFF_W1BF);

    // 4 dispatches; spread-atomic stats; grids 2048 on the prep MFMA kernels
    // (T-lat retest: r10's 2048-grid base was ~22.6 us once the atomic tail is
    //  subtracted; the tail itself is now ~1 us with NCOPY=32 spreading)
    hist_k<<<259, 256, 0, stream>>>(idx, pc, W2, w2bf, W1, w1bf, sp1, sp2);
    gemm1_k<<<2048, 256, 0, stream>>>(feat, w1bf, b1, pc, counts, z1b, sp1);
    stats2_k<<<2048, 256, 0, stream>>>(z1b, w2bf, sp1, g1, be1, b2, counts, hb, sp2);
    fused_k<<<2048, 256, 0, stream>>>(hb, w2bf, idx, b2, sp2, g2, be2, out);
}

// Round 13
// 176.754 us; speedup vs baseline: 1.0614x; 1.0614x over previous
//
#include <hip/hip_runtime.h>
#include <hip/hip_bf16.h>

#define N_PTS 100000
#define KNN   16
#define NK    (N_PTS * KNN)
#define CIN   64
#define CMID  64
#define COUT  128

#define HSLC    64           // histogram slices (r4-proven)
#define SEG_CNT 25000        // counters per segment (4 segments cover 100k)
#define SEG_U32 12500

#define NCOPY 32             // spread-atomic copies (kills same-line RMW serialization)

// ---------------- ws layout (bytes) ----------------
// [0, +12,800,000)          pc: 64 x 100k ushort partials (dead after gemm1);
//                           reused as hb: N*64 bf16 = bf16(relu(z1*A1+B1))
// [13,000,000, +16,384)     SP1: [32][128] float stat1 partial copies (zeroed by hist)
// [13,100,000, +32,768)     SP2: [32][256] float stat2 partial copies (zeroed by hist)
// [13,200,000, +16,384)     W2bf32: 32x32-B-frag-swizzled W2 (bf16) for fused_k
// [25,600,000, +12,800,000) z1b (N*64 bf16, row-major)
// [38,400,000, +400,000)    counts (float, written by gemm1 for stats2)
// [38,801,536, +16,384)     W2bf: 16x16-B-frag-swizzled W2 (bf16) for stats2
// [38,817,920, +8,192)      W1bf: B-frag-swizzled W1 (bf16)
#define OFF_PC     0
#define OFF_HB     0
#define OFF_SP1    13000000
#define OFF_SP2    13100000
#define OFF_W2BF32 13200000
#define OFF_Z1B    25600000
#define OFF_CNT    38400000
#define OFF_W2BF   38801536
#define OFF_W1BF   38817920

typedef __attribute__((ext_vector_type(8))) short bf16x8;
typedef __attribute__((ext_vector_type(4))) float f32x4;
typedef __attribute__((ext_vector_type(16))) float f32x16;
union U8 { uint4 u; bf16x8 v; unsigned short s[8]; };

__device__ __forceinline__ unsigned short f2bf(float f) {
    unsigned u = __float_as_uint(f);
    unsigned r = (u + 0x7fffu + ((u >> 16) & 1u)) >> 16;   // RNE
    return (unsigned short)r;
}

// ---- D1. hist_k: 256 hist blocks + swizzles (256/257) + zero SP (258) ----
__global__ __launch_bounds__(256) void hist_k(const int* __restrict__ idx,
                                              unsigned short* __restrict__ pc,
                                              const float* __restrict__ W2,
                                              unsigned short* __restrict__ w2bf,
                                              unsigned short* __restrict__ w2bf32,
                                              const float* __restrict__ W1,
                                              unsigned short* __restrict__ w1bf,
                                              float* __restrict__ sp1,
                                              float* __restrict__ sp2) {
    if (blockIdx.x >= 256) {
        if (blockIdx.x == 256) {
            // 16x16 B-frag (stats2): e = ((nt*2+kh)*64 + lane)*8 + j
            for (int e = threadIdx.x; e < 8192; e += 256) {
                int j = e & 7, lane = (e >> 3) & 63, kh = (e >> 9) & 1, nt = e >> 10;
                int k = kh * 32 + (lane >> 4) * 8 + j;
                int n = nt * 16 + (lane & 15);
                w2bf[e] = f2bf(W2[k * COUT + n]);
            }
            // 32x32 B-frag (fused): e = ((nt2*4+kc)*64 + lane)*8 + j
            // B[k][n]: k = kc*16 + (lane>>5)*8 + j, n = nt2*32 + (lane&31)
            for (int e = threadIdx.x; e < 8192; e += 256) {
                int j = e & 7, lane = (e >> 3) & 63, f = e >> 9;
                int kc = f & 3, nt2 = f >> 2;
                int k = kc * 16 + (lane >> 5) * 8 + j;
                int n = nt2 * 32 + (lane & 31);
                w2bf32[e] = f2bf(W2[k * COUT + n]);
            }
        } else if (blockIdx.x == 257) {
            for (int e = threadIdx.x; e < 4096; e += 256) {
                int j = e & 7, lane = (e >> 3) & 63, kh = (e >> 9) & 1, nt = e >> 10;
                int k = kh * 32 + (lane >> 4) * 8 + j;
                int n = nt * 16 + (lane & 15);
                w1bf[e] = f2bf(W1[k * CMID + n]);
            }
        } else {
            for (int i = threadIdx.x; i < NCOPY * 128; i += 256) sp1[i] = 0.f;
            for (int i = threadIdx.x; i < NCOPY * 256; i += 256) sp2[i] = 0.f;
        }
        return;
    }
    __shared__ unsigned int smem[SEG_U32];     // 50 KB
    int seg  = blockIdx.x & 3;
    int slc  = blockIdx.x >> 2;                // 0..63
    int base = seg * SEG_CNT;

    for (int i = threadIdx.x; i < SEG_U32; i += 256) smem[i] = 0;
    __syncthreads();

    const int4* ip = (const int4*)idx;
    const int per = NK / 4 / HSLC;             // 6250 int4 per slice
    int s = slc * per, e = s + per;
    for (int i = s + threadIdx.x; i < e; i += 256) {
        int4 v = ip[i];
        int a;
        a = v.x - base; if ((unsigned)a < (unsigned)SEG_CNT)
            atomicAdd(&smem[a >> 1], 1u << ((a & 1) * 16));
        a = v.y - base; if ((unsigned)a < (unsigned)SEG_CNT)
            atomicAdd(&smem[a >> 1], 1u << ((a & 1) * 16));
        a = v.z - base; if ((unsigned)a < (unsigned)SEG_CNT)
            atomicAdd(&smem[a >> 1], 1u << ((a & 1) * 16));
        a = v.w - base; if ((unsigned)a < (unsigned)SEG_CNT)
            atomicAdd(&smem[a >> 1], 1u << ((a & 1) * 16));
    }
    __syncthreads();

    unsigned int* outp = (unsigned int*)(pc + (size_t)slc * N_PTS) + seg * SEG_U32;
    for (int i = threadIdx.x; i < SEG_U32; i += 256) outp[i] = smem[i];
}

// ---- D2. gemm1_k (r11-proven, grid 512): counts from pc; z1b; stats1 -> SP1 ----
__global__ __launch_bounds__(256) void gemm1_k(const float* __restrict__ feat,
                                               const unsigned short* __restrict__ w1bf,
                                               const float* __restrict__ b1,
                                               const unsigned short* __restrict__ pc,
                                               float* __restrict__ counts,
                                               unsigned short* __restrict__ z1b,
                                               float* __restrict__ sp1) {
    int lane = threadIdx.x & 63, wid = threadIdx.x >> 6;
    int il = lane & 15, quad = lane >> 4;

    bf16x8 wf[4][2];
    const uint4* wp = (const uint4*)w1bf;
    #pragma unroll
    for (int nt = 0; nt < 4; nt++) {
        U8 t0; t0.u = wp[(nt * 2 + 0) * 64 + lane]; wf[nt][0] = t0.v;
        U8 t1; t1.u = wp[(nt * 2 + 1) * 64 + lane]; wf[nt][1] = t1.v;
    }
    float bias[4];
    #pragma unroll
    for (int nt = 0; nt < 4; nt++) bias[nt] = b1[nt * 16 + il];

    float s[4] = {0, 0, 0, 0}, q[4] = {0, 0, 0, 0};

    int wgid = blockIdx.x * 4 + wid;
    for (int tile = wgid; tile < N_PTS / 16; tile += gridDim.x * 4) {
        int m0 = tile * 16;

        const uint4* pcp = (const uint4*)(pc + (size_t)lane * N_PTS + m0);
        uint4 pa = pcp[0], pb = pcp[1];
        #pragma unroll
        for (int m = 1; m < 64; m <<= 1) {
            pa.x += __shfl_xor(pa.x, m, 64);
            pa.y += __shfl_xor(pa.y, m, 64);
            pa.z += __shfl_xor(pa.z, m, 64);
            pa.w += __shfl_xor(pa.w, m, 64);
            pb.x += __shfl_xor(pb.x, m, 64);
            pb.y += __shfl_xor(pb.y, m, 64);
            pb.z += __shfl_xor(pb.z, m, 64);
            pb.w += __shfl_xor(pb.w, m, 64);
        }
        unsigned w0 = (quad == 0) ? pa.x : (quad == 1) ? pa.z : (quad == 2) ? pb.x : pb.z;
        unsigned w1 = (quad == 0) ? pa.y : (quad == 1) ? pa.w : (quad == 2) ? pb.y : pb.w;
        float4 cnt4;
        cnt4.x = (float)(w0 & 0xffffu);
        cnt4.y = (float)(w0 >> 16);
        cnt4.z = (float)(w1 & 0xffffu);
        cnt4.w = (float)(w1 >> 16);
        if (il == 0) ((float4*)(counts + m0))[quad] = cnt4;

        const float* fr = feat + (size_t)(m0 + il) * 64;
        float4 fa = *(const float4*)(fr + quad * 8);
        float4 fb = *(const float4*)(fr + quad * 8 + 4);
        float4 fc = *(const float4*)(fr + 32 + quad * 8);
        float4 fd = *(const float4*)(fr + 32 + quad * 8 + 4);
        U8 ua, ub;
        ua.s[0] = f2bf(fa.x); ua.s[1] = f2bf(fa.y); ua.s[2] = f2bf(fa.z); ua.s[3] = f2bf(fa.w);
        ua.s[4] = f2bf(fb.x); ua.s[5] = f2bf(fb.y); ua.s[6] = f2bf(fb.z); ua.s[7] = f2bf(fb.w);
        ub.s[0] = f2bf(fc.x); ub.s[1] = f2bf(fc.y); ub.s[2] = f2bf(fc.z); ub.s[3] = f2bf(fc.w);
        ub.s[4] = f2bf(fd.x); ub.s[5] = f2bf(fd.y); ub.s[6] = f2bf(fd.z); ub.s[7] = f2bf(fd.w);

        #pragma unroll
        for (int nt = 0; nt < 4; nt++) {
            f32x4 acc = {bias[nt], bias[nt], bias[nt], bias[nt]};
            acc = __builtin_amdgcn_mfma_f32_16x16x32_bf16(ua.v, wf[nt][0], acc, 0, 0, 0);
            acc = __builtin_amdgcn_mfma_f32_16x16x32_bf16(ub.v, wf[nt][1], acc, 0, 0, 0);
            unsigned short* zp = z1b + (size_t)(m0 + quad * 4) * 64 + nt * 16 + il;
            zp[0]   = f2bf(acc[0]);
            zp[64]  = f2bf(acc[1]);
            zp[128] = f2bf(acc[2]);
            zp[192] = f2bf(acc[3]);
            s[nt] += cnt4.x * acc[0] + cnt4.y * acc[1] + cnt4.z * acc[2] + cnt4.w * acc[3];
            q[nt] += cnt4.x * acc[0] * acc[0] + cnt4.y * acc[1] * acc[1]
                   + cnt4.z * acc[2] * acc[2] + cnt4.w * acc[3] * acc[3];
        }
    }
    #pragma unroll
    for (int m = 16; m <= 32; m <<= 1) {
        #pragma unroll
        for (int nt = 0; nt < 4; nt++) {
            s[nt] += __shfl_xor(s[nt], m, 64);
            q[nt] += __shfl_xor(q[nt], m, 64);
        }
    }
    __shared__ float sred[2][4][4][16];
    if (quad == 0) {
        #pragma unroll
        for (int nt = 0; nt < 4; nt++) { sred[0][wid][nt][il] = s[nt]; sred[1][wid][nt][il] = q[nt]; }
    }
    __syncthreads();
    if (threadIdx.x < 128) {
        int which = threadIdx.x >> 6, c = threadIdx.x & 63;
        float t = sred[which][0][c >> 4][c & 15] + sred[which][1][c >> 4][c & 15]
                + sred[which][2][c >> 4][c & 15] + sred[which][3][c >> 4][c & 15];
        atomicAdd(&sp1[(blockIdx.x & (NCOPY - 1)) * 128 + threadIdx.x], t);
    }
}

// ---- D3. stats2_k (r11-proven, grid 512): SP1->BN1; hb; stats2 -> SP2 ----
__device__ __forceinline__ bf16x8 bnrelu(uint4 r, float4 alo, float4 ahi,
                                         float4 blo, float4 bhi) {
    float z0 = __uint_as_float(r.x << 16), z1 = __uint_as_float(r.x & 0xffff0000u);
    float z2 = __uint_as_float(r.y << 16), z3 = __uint_as_float(r.y & 0xffff0000u);
    float z4 = __uint_as_float(r.z << 16), z5 = __uint_as_float(r.z & 0xffff0000u);
    float z6 = __uint_as_float(r.w << 16), z7 = __uint_as_float(r.w & 0xffff0000u);
    U8 o;
    o.s[0] = f2bf(fmaxf(fmaf(alo.x, z0, blo.x), 0.f));
    o.s[1] = f2bf(fmaxf(fmaf(alo.y, z1, blo.y), 0.f));
    o.s[2] = f2bf(fmaxf(fmaf(alo.z, z2, blo.z), 0.f));
    o.s[3] = f2bf(fmaxf(fmaf(alo.w, z3, blo.w), 0.f));
    o.s[4] = f2bf(fmaxf(fmaf(ahi.x, z4, bhi.x), 0.f));
    o.s[5] = f2bf(fmaxf(fmaf(ahi.y, z5, bhi.y), 0.f));
    o.s[6] = f2bf(fmaxf(fmaf(ahi.z, z6, bhi.z), 0.f));
    o.s[7] = f2bf(fmaxf(fmaf(ahi.w, z7, bhi.w), 0.f));
    return o.v;
}

__global__ __launch_bounds__(256) void stats2_k(const unsigned short* __restrict__ z1b,
                                                const unsigned short* __restrict__ w2bf,
                                                const float* __restrict__ sp1,
                                                const float* __restrict__ g1,
                                                const float* __restrict__ be1,
                                                const float* __restrict__ b2,
                                                const float* __restrict__ counts,
                                                unsigned short* __restrict__ hb,
                                                float* __restrict__ sp2) {
    __shared__ float Sl[128];
    __shared__ float Al[64], Bl[64];
    if (threadIdx.x < 128) {
        float t = 0.f;
        #pragma unroll
        for (int k = 0; k < NCOPY; k++) t += sp1[k * 128 + threadIdx.x];
        Sl[threadIdx.x] = t;
    }
    __syncthreads();
    if (threadIdx.x < 64) {
        const float inv = 1.0f / (float)NK;
        float m = Sl[threadIdx.x] * inv;
        float v = Sl[64 + threadIdx.x] * inv - m * m;
        float a = g1[threadIdx.x] * rsqrtf(v + 1e-5f);
        Al[threadIdx.x] = a;
        Bl[threadIdx.x] = be1[threadIdx.x] - m * a;
    }
    __syncthreads();

    int lane = threadIdx.x & 63, wid = threadIdx.x >> 6;
    int il = lane & 15, quad = lane >> 4;

    float4 a0lo = *(const float4*)(Al + quad * 8);
    float4 a0hi = *(const float4*)(Al + quad * 8 + 4);
    float4 b0lo = *(const float4*)(Bl + quad * 8);
    float4 b0hi = *(const float4*)(Bl + quad * 8 + 4);
    float4 a1lo = *(const float4*)(Al + 32 + quad * 8);
    float4 a1hi = *(const float4*)(Al + 32 + quad * 8 + 4);
    float4 b1lo = *(const float4*)(Bl + 32 + quad * 8);
    float4 b1hi = *(const float4*)(Bl + 32 + quad * 8 + 4);

    bf16x8 bfr[8][2];
    const uint4* wp = (const uint4*)w2bf;
    #pragma unroll
    for (int nt = 0; nt < 8; nt++) {
        U8 t0; t0.u = wp[(nt * 2 + 0) * 64 + lane]; bfr[nt][0] = t0.v;
        U8 t1; t1.u = wp[(nt * 2 + 1) * 64 + lane]; bfr[nt][1] = t1.v;
    }
    float bias[8];
    #pragma unroll
    for (int nt = 0; nt < 8; nt++) bias[nt] = b2[nt * 16 + il];

    float s[8], q[8];
    #pragma unroll
    for (int j = 0; j < 8; j++) { s[j] = 0.f; q[j] = 0.f; }

    int wgid = blockIdx.x * 4 + wid;
    for (int tile = wgid; tile < N_PTS / 16; tile += gridDim.x * 4) {
        int m0 = tile * 16;
        const uint4* ar = (const uint4*)(z1b + (size_t)(m0 + il) * 64);
        uint4 ra0 = ar[quad];
        uint4 ra1 = ar[4 + quad];
        bf16x8 af0 = bnrelu(ra0, a0lo, a0hi, b0lo, b0hi);
        bf16x8 af1 = bnrelu(ra1, a1lo, a1hi, b1lo, b1hi);
        U8 o0; o0.v = af0;
        U8 o1; o1.v = af1;
        uint4* hp = (uint4*)(hb + (size_t)(m0 + il) * 64);
        hp[quad]     = o0.u;
        hp[4 + quad] = o1.u;
        float4 cnt4 = *(const float4*)(counts + m0 + quad * 4);
        #pragma unroll
        for (int nt = 0; nt < 8; nt++) {
            f32x4 acc = {bias[nt], bias[nt], bias[nt], bias[nt]};
            acc = __builtin_amdgcn_mfma_f32_16x16x32_bf16(af0, bfr[nt][0], acc, 0, 0, 0);
            acc = __builtin_amdgcn_mfma_f32_16x16x32_bf16(af1, bfr[nt][1], acc, 0, 0, 0);
            s[nt] += cnt4.x * acc[0] + cnt4.y * acc[1] + cnt4.z * acc[2] + cnt4.w * acc[3];
            q[nt] += cnt4.x * acc[0] * acc[0] + cnt4.y * acc[1] * acc[1]
                   + cnt4.z * acc[2] * acc[2] + cnt4.w * acc[3] * acc[3];
        }
    }
    #pragma unroll
    for (int m = 16; m <= 32; m <<= 1) {
        #pragma unroll
        for (int nt = 0; nt < 8; nt++) {
            s[nt] += __shfl_xor(s[nt], m, 64);
            q[nt] += __shfl_xor(q[nt], m, 64);
        }
    }
    __shared__ float sred[2][4][8][16];
    if (quad == 0) {
        #pragma unroll
        for (int nt = 0; nt < 8; nt++) { sred[0][wid][nt][il] = s[nt]; sred[1][wid][nt][il] = q[nt]; }
    }
    __syncthreads();
    {
        int which = threadIdx.x >> 7, c = threadIdx.x & 127;
        float t = sred[which][0][c >> 4][c & 15] + sred[which][1][c >> 4][c & 15]
                + sred[which][2][c >> 4][c & 15] + sred[which][3][c >> 4][c & 15];
        atomicAdd(&sp2[(blockIdx.x & (NCOPY - 1)) * 256 + threadIdx.x], t);
    }
}

// ---- D4. fused_k: 32x32x16 MFMA, 2 points/wave ----
// A-tile = 32 rows (16 nbrs of point A + 16 of point B) x 64 chans.
// Lane l: A row = l&31 (point (l>>4)&1, nbr l&15), k-half = l>>5.
// C/D (HW-verified): col=lane&31, row=(reg&3)+8*(reg>>2)+4*(lane>>5) ->
// regs 0..7 = point A rows, 8..15 = point B rows; cross-hi reduce = 1 shfl_xor(32).
// Epilogue shfls per point: 16 -> 4. MFMA instr per point: 16 -> 8.
__global__ __launch_bounds__(256) void fused_k(const unsigned short* __restrict__ hb,
                                               const unsigned short* __restrict__ w2bf32,
                                               const int* __restrict__ idx,
                                               const float* __restrict__ b2,
                                               const float* __restrict__ sp2,
                                               const float* __restrict__ g2,
                                               const float* __restrict__ be2,
                                               float* __restrict__ out) {
    __shared__ float S2l[256];
    __shared__ float A2s[128], B2f[128];
    __shared__ uint4 wlds[1024];               // 16 KB staged (sign-folded) W2 32x32 B-frags

    {
        float t = 0.f;
        #pragma unroll
        for (int k = 0; k < NCOPY; k++) t += sp2[k * 256 + threadIdx.x];
        S2l[threadIdx.x] = t;
    }
    __syncthreads();
    const float inv = 1.0f / (float)NK;
    if (threadIdx.x < 128) {
        int c = threadIdx.x;
        float m = S2l[c] * inv;
        float v = S2l[128 + c] * inv - m * m;
        float a = g2[c] * rsqrtf(v + 1e-5f);
        A2s[c] = a;
        B2f[c] = fmaf(a, b2[c], be2[c] - m * a);   // fold b2: max(z2)=max(raw)+b2
    }
    __syncthreads();

    // stage W2 32x32 frags, sign-folding columns with a2<0.
    // uint4 i: frag f = i>>6, lane_i = i&63; col = (i>>8)*32 + (i&31)
    for (int i = threadIdx.x; i < 1024; i += 256) {
        uint4 w = ((const uint4*)w2bf32)[i];
        int c = ((i >> 8) << 5) + (i & 31);
        if (A2s[c] < 0.f) {
            w.x ^= 0x80008000u; w.y ^= 0x80008000u;
            w.z ^= 0x80008000u; w.w ^= 0x80008000u;
        }
        wlds[i] = w;
    }
    __syncthreads();

    int lane = threadIdx.x & 63, wid = threadIdx.x >> 6;
    int r32 = lane & 31;                       // A row / output col-within-tile
    int hi  = lane >> 5;                       // k-half; also point selector at epilogue
    int pl  = (lane >> 4) & 1;                 // which point this lane's A row is
    int nb  = lane & 15;                       // neighbor slot

    bf16x8 bfr[4][4];                          // [nt2][kc]
    #pragma unroll
    for (int nt2 = 0; nt2 < 4; nt2++) {
        #pragma unroll
        for (int kc = 0; kc < 4; kc++) {
            U8 t; t.u = wlds[(nt2 * 4 + kc) * 64 + lane];
            bfr[nt2][kc] = t.v;
        }
    }
    float a2c[4], b2c[4];
    #pragma unroll
    for (int nt2 = 0; nt2 < 4; nt2++) {
        a2c[nt2] = fabsf(A2s[nt2 * 32 + r32]);
        b2c[nt2] = B2f[nt2 * 32 + r32];
    }

    const int NPAIRS = N_PTS / 2;              // 50000
    const int stride = gridDim.x * 4;
    int pair = blockIdx.x * 4 + wid;
    int p1 = pair + stride;

    // pipeline prologue: rows for pair, idx for p1
    uint4 rc0 = {0,0,0,0}, rc1 = {0,0,0,0}, rc2 = {0,0,0,0}, rc3 = {0,0,0,0};
    if (pair < NPAIRS) {
        int j0 = idx[(size_t)(pair * 2 + pl) * KNN + nb];
        const uint4* zr = (const uint4*)hb + (size_t)j0 * 8;
        rc0 = zr[0 + hi]; rc1 = zr[2 + hi]; rc2 = zr[4 + hi]; rc3 = zr[6 + hi];
    }
    int j1 = (p1 < NPAIRS) ? idx[(size_t)(p1 * 2 + pl) * KNN + nb] : 0;

    while (pair < NPAIRS) {
        // prefetch rows for p1, idx for p2
        uint4 rn0 = {0,0,0,0}, rn1 = {0,0,0,0}, rn2 = {0,0,0,0}, rn3 = {0,0,0,0};
        int p2 = p1 + stride;
        if (p1 < NPAIRS) {
            const uint4* zr = (const uint4*)hb + (size_t)j1 * 8;
            rn0 = zr[0 + hi]; rn1 = zr[2 + hi]; rn2 = zr[4 + hi]; rn3 = zr[6 + hi];
        }
        int j2 = (p2 < NPAIRS) ? idx[(size_t)(p2 * 2 + pl) * KNN + nb] : 0;

        // compute current pair
        U8 a0, a1, a2, a3;
        a0.u = rc0; a1.u = rc1; a2.u = rc2; a3.u = rc3;
        #pragma unroll
        for (int nt2 = 0; nt2 < 4; nt2++) {
            f32x16 acc = {0.f,0.f,0.f,0.f,0.f,0.f,0.f,0.f,0.f,0.f,0.f,0.f,0.f,0.f,0.f,0.f};
            acc = __builtin_amdgcn_mfma_f32_32x32x16_bf16(a0.v, bfr[nt2][0], acc, 0, 0, 0);
            acc = __builtin_amdgcn_mfma_f32_32x32x16_bf16(a1.v, bfr[nt2][1], acc, 0, 0, 0);
            acc = __builtin_amdgcn_mfma_f32_32x32x16_bf16(a2.v, bfr[nt2][2], acc, 0, 0, 0);
            acc = __builtin_amdgcn_mfma_f32_32x32x16_bf16(a3.v, bfr[nt2][3], acc, 0, 0, 0);
            // regs 0..7 -> point A rows; 8..15 -> point B rows
            float mxA = fmaxf(fmaxf(fmaxf(acc[0], acc[1]), fmaxf(acc[2], acc[3])),
                              fmaxf(fmaxf(acc[4], acc[5]), fmaxf(acc[6], acc[7])));
            float mxB = fmaxf(fmaxf(fmaxf(acc[8], acc[9]), fmaxf(acc[10], acc[11])),
                              fmaxf(fmaxf(acc[12], acc[13]), fmaxf(acc[14], acc[15])));
            mxA = fmaxf(mxA, __shfl_xor(mxA, 32, 64));
            mxB = fmaxf(mxB, __shfl_xor(mxB, 32, 64));
            float vA = fmaxf(fmaf(a2c[nt2], mxA, b2c[nt2]), 0.f);
            float vB = fmaxf(fmaf(a2c[nt2], mxB, b2c[nt2]), 0.f);
            float vv = hi ? vB : vA;
            int np = pair * 2 + hi;
            __builtin_nontemporal_store(vv, out + (size_t)np * COUT + nt2 * 32 + r32);
        }

        pair = p1; p1 = p2; j1 = j2;
        rc0 = rn0; rc1 = rn1; rc2 = rn2; rc3 = rn3;
    }
}

extern "C" void kernel_launch(void* const* d_in, const int* in_sizes, int n_in,
                              void* d_out, int out_size, void* d_ws, size_t ws_size,
                              hipStream_t stream) {
    const float* feat = (const float*)d_in[0];
    const int*   idx  = (const int*)d_in[1];
    const float* W1   = (const float*)d_in[2];
    const float* b1   = (const float*)d_in[3];
    const float* g1   = (const float*)d_in[4];
    const float* be1  = (const float*)d_in[5];
    const float* W2   = (const float*)d_in[6];
    const float* b2   = (const float*)d_in[7];
    const float* g2   = (const float*)d_in[8];
    const float* be2  = (const float*)d_in[9];
    float* out = (float*)d_out;

    char* ws = (char*)d_ws;
    unsigned short* pc  = (unsigned short*)(ws + OFF_PC);
    unsigned short* hb  = (unsigned short*)(ws + OFF_HB);    // alias, pc dead after gemm1
    float* sp1 = (float*)(ws + OFF_SP1);
    float* sp2 = (float*)(ws + OFF_SP2);
    unsigned short* w2bf32 = (unsigned short*)(ws + OFF_W2BF32);
    unsigned short* z1b = (unsigned short*)(ws + OFF_Z1B);
    float* counts = (float*)(ws + OFF_CNT);
    unsigned short* w2bf = (unsigned short*)(ws + OFF_W2BF);
    unsigned short* w1bf = (unsigned short*)(ws + OFF_W1BF);

    // 4 dispatches; r11-proven grids (512 on prep — r12 showed 2048 hurts)
    hist_k<<<259, 256, 0, stream>>>(idx, pc, W2, w2bf, w2bf32, W1, w1bf, sp1, sp2);
    gemm1_k<<<512, 256, 0, stream>>>(feat, w1bf, b1, pc, counts, z1b, sp1);
    stats2_k<<<512, 256, 0, stream>>>(z1b, w2bf, sp1, g1, be1, b2, counts, hb, sp2);
    fused_k<<<2048, 256, 0, stream>>>(hb, w2bf32, idx, b2, sp2, g2, be2, out);
}